// Round 1
// baseline (468.413 us; speedup 1.0000x reference)
//
#include <hip/hip_runtime.h>
#include <hip/hip_bf16.h>

#define B_   32
#define C_   64
#define H_   96
#define W_   96
#define K_   32
#define R_   13
#define HO_  84
#define WO_  84
#define HW_  (H_*W_)      // 9216
#define OHW_ (HO_*WO_)    // 7056
#define CRR_ (C_*R_*R_)   // 10816
#define RR_  (R_*R_)      // 169

#define TILE_ 16
#define PW_   28          // patch height/width = TILE_+12
#define NPIX_ (PW_*PW_)   // 784
#define XS_BYTES (NPIX_*128)           // 100352: [pixel][64c] bf16, slot-swizzled
#define US_BYTES 4096                  // [32k][64c] bf16, slot-swizzled
#define LDS_BYTES (XS_BYTES + 2*US_BYTES)  // 108544

typedef unsigned int u32;
typedef unsigned short u16;
typedef __attribute__((ext_vector_type(16))) float f32x16;
typedef __attribute__((ext_vector_type(4))) u32 u32x4;
typedef __attribute__((ext_vector_type(2))) u32 u32x2;

static __device__ __forceinline__ u16 f2bf(float v){
    __hip_bfloat16 h = __float2bfloat16(v);  // RNE
    return *reinterpret_cast<u16*>(&h);
}

// D = A*B + D  (32x32x16 bf16).  Inline asm sidesteps builtin signature variance.
#define MFMA(acc, a, b) asm("v_mfma_f32_32x32x16_bf16 %0, %1, %2, %0" \
                            : "+v"(acc) : "v"(a), "v"(b))

// ---------------- k1: y-norms + swizzled bf16 prototype tensor -------------
// u_g layout: [ij][k][128B row]; byte in row = ((c>>3)^(k&7))*16 + (c&7)*2
__global__ void k_prep_y(const float* __restrict__ y, unsigned char* __restrict__ u_g){
    int k = blockIdx.x, tid = threadIdx.x;
    const float* yk = y + (size_t)k * CRR_;
    float ss = 0.f;
    for (int idx = tid; idx < CRR_; idx += 256){ float v = yk[idx]; ss += v*v; }
    for (int off = 32; off; off >>= 1) ss += __shfl_down(ss, off);
    __shared__ float red[4];
    if ((tid & 63) == 0) red[tid >> 6] = ss;
    __syncthreads();
    float inv = 1.f / fmaxf(sqrtf(red[0]+red[1]+red[2]+red[3]), 1e-9f);

    int c = tid & 63, grp = tid >> 6;                 // 64 c-lanes x 4 ij-groups
    int swz = ((((c >> 3) ^ (k & 7)) << 4) | ((c & 7) << 1));
    for (int base = 0; base < RR_; base += 4){
        int ij = base + grp;
        if (ij < RR_){
            float v = yk[c*RR_ + ij] * inv;
            *(u16*)(u_g + (size_t)ij*4096 + k*128 + swz) = f2bf(v);
        }
    }
}

// ---------------- k2: s[b,y,x] = sum_c x^2 (fp32 exact) --------------------
__global__ void k_sq(const float* __restrict__ x, float* __restrict__ s){
    int idx = blockIdx.x*256 + threadIdx.x;           // < 294912 exact
    int b = idx / HW_, r = idx % HW_;
    const float* xb = x + (size_t)b * C_ * HW_;
    float acc = 0.f;
    #pragma unroll
    for (int c = 0; c < C_; ++c){ float v = xb[(size_t)c*HW_ + r]; acc += v*v; }
    s[idx] = acc;
}

// ---------------- k3: inv_xn = 1/max(sqrt(13x13 box sum), eps) -------------
__global__ void k_inv(const float* __restrict__ s, float* __restrict__ inv_xn){
    int idx = blockIdx.x*256 + threadIdx.x;           // < 225792 exact
    int b = idx / OHW_, r = idx % OHW_;
    int oh = r / WO_, ow = r % WO_;
    const float* sb = s + (size_t)b*HW_ + oh*W_ + ow;
    float acc = 0.f;
    for (int i = 0; i < R_; ++i){
        #pragma unroll
        for (int j = 0; j < R_; ++j) acc += sb[i*W_ + j];
    }
    inv_xn[idx] = 1.f / fmaxf(sqrtf(acc), 1e-9f);
}

// ---------------- k_main: fused cosine-similarity conv ---------------------
// Block: b x 16x16 output tile, 512 thr (8 waves). Wave w: local rows 2w,2w+1,
// cols 0..15 (B spatial j = (lane>>4&1)*16+(lane&15), matches D col=lane&31).
__launch_bounds__(512, 1)
__global__ void k_main(const float* __restrict__ x, const unsigned char* __restrict__ u_g,
                       const float* __restrict__ inv_xn, float* __restrict__ out){
    extern __shared__ unsigned char lds[];
    unsigned char* xs = lds;
    unsigned char* us = lds + XS_BYTES;

    int bb = blockIdx.x;
    int b  = bb / 36;
    int tt = bb % 36;
    int oy = (tt / 6) * TILE_;
    int ox = (tt % 6) * TILE_;

    int tid  = threadIdx.x;
    int lane = tid & 63;
    int wv   = tid >> 6;        // 0..7
    int ks   = lane >> 5;       // k-half of MFMA operands
    int rb   = (lane >> 4) & 1; // row offset within wave's 2-row strip
    int cx   = lane & 15;       // col
    int kpr  = lane & 31;       // prototype row for A-frag

    // ---- stage x patch: fp32 global -> bf16 LDS, swizzled, b128 writes ----
    const float* xb = x + (size_t)b * C_ * HW_;
    for (int p = tid; p < NPIX_; p += 512){
        int py = p / PW_, px = p % PW_;
        int gy = oy + py; if (gy > H_-1) gy = H_-1;   // clamp: only feeds invalid outputs
        int gx = ox + px; if (gx > W_-1) gx = W_-1;
        const float* src = xb + gy*W_ + gx;
        unsigned char* dst = xs + p*128;
        int psw = p & 7;
        #pragma unroll
        for (int sl = 0; sl < 8; ++sl){
            int c0 = sl*8;
            u32 w0 = f2bf(src[(size_t)(c0+0)*HW_]) | ((u32)f2bf(src[(size_t)(c0+1)*HW_]) << 16);
            u32 w1 = f2bf(src[(size_t)(c0+2)*HW_]) | ((u32)f2bf(src[(size_t)(c0+3)*HW_]) << 16);
            u32 w2 = f2bf(src[(size_t)(c0+4)*HW_]) | ((u32)f2bf(src[(size_t)(c0+5)*HW_]) << 16);
            u32 w3 = f2bf(src[(size_t)(c0+6)*HW_]) | ((u32)f2bf(src[(size_t)(c0+7)*HW_]) << 16);
            u32x4 q = {w0, w1, w2, w3};
            *(u32x4*)(dst + ((sl ^ psw) << 4)) = q;
        }
    }

    // preload u-slice for ij=0 (linear copy; swizzle pre-baked in global)
    { u32x2 v = *(const u32x2*)(u_g + tid*8); *(u32x2*)(us + tid*8) = v; }
    __syncthreads();

    f32x16 acc = {};
    int baseA = (kpr << 7) ^ ((ks ^ (kpr & 7)) << 4);   // loop-invariant A addr
    int pb = (2*wv + rb) * PW_ + cx;

    int ij = 0;
    for (int i = 0; i < R_; ++i){
        int prow = pb + i*PW_;
        for (int jx = 0; jx < R_; ++jx, ++ij){
            // T14: issue next u-slice load early, write to LDS after compute
            u32x2 nv;
            bool have = (ij + 1 < RR_);
            if (have) nv = *(const u32x2*)(u_g + (size_t)(ij+1)*4096 + tid*8);

            const unsigned char* usb = us + (ij & 1)*US_BYTES;
            int p = prow + jx;
            int baseB = (p << 7) ^ ((ks ^ (p & 7)) << 4);
            #pragma unroll
            for (int cc = 0; cc < 4; ++cc){
                u32x4 av = *(const u32x4*)(usb + (baseA ^ (cc << 5)));
                u32x4 bv = *(const u32x4*)(xs  + (baseB ^ (cc << 5)));
                MFMA(acc, av, bv);
            }
            if (have) *(u32x2*)(us + ((ij+1) & 1)*US_BYTES + tid*8) = nv;
            __syncthreads();   // single barrier/tap: publishes next buf, fences cur buf
        }
    }

    // ---- epilogue: relu(num) * 1/||x_win||, D layout col=lane&31,
    // row = (r&3) + 8*(r>>2) + 4*(lane>>5)  [m74/m101 verified] ----
    int oh = oy + 2*wv + rb;
    int ow = ox + cx;
    bool valid = (oh < HO_) && (ow < WO_);
    float inv = 0.f;
    if (valid) inv = inv_xn[(size_t)b*OHW_ + oh*WO_ + ow];
    float* ob = out + (size_t)b*K_*OHW_ + oh*WO_ + ow;
    #pragma unroll
    for (int r = 0; r < 16; ++r){
        int kp = (r & 3) + 8*(r >> 2) + 4*ks;
        if (valid) ob[(size_t)kp*OHW_] = fmaxf(acc[r], 0.f) * inv;
    }
}

extern "C" void kernel_launch(void* const* d_in, const int* in_sizes, int n_in,
                              void* d_out, int out_size, void* d_ws, size_t ws_size,
                              hipStream_t stream) {
    const float* x = (const float*)d_in[0];
    const float* y = (const float*)d_in[1];
    float* out = (float*)d_out;
    unsigned char* ws = (unsigned char*)d_ws;

    unsigned char* u_g   = ws;                                   // 692224 B
    float*         s     = (float*)(ws + 692224);                // 1179648 B
    float*         invxn = (float*)(ws + 692224 + 1179648);      // 903168 B

    k_prep_y<<<K_, 256, 0, stream>>>(y, u_g);
    k_sq<<<(B_*HW_)/256, 256, 0, stream>>>(x, s);
    k_inv<<<(B_*OHW_)/256, 256, 0, stream>>>(s, invxn);

    // >64KB dynamic LDS opt-in (gfx950 allows 160KB/WG; m201 used 128KB)
    hipFuncSetAttribute(reinterpret_cast<const void*>(k_main),
                        hipFuncAttributeMaxDynamicSharedMemorySize, LDS_BYTES);
    k_main<<<B_*36, 512, LDS_BYTES, stream>>>(x, u_g, invxn, out);
}